// Round 3
// baseline (766.775 us; speedup 1.0000x reference)
//
#include <hip/hip_runtime.h>
#include <hip/hip_bf16.h>

#define NB 32
#define NT 2048
#define NH 1024

typedef __attribute__((ext_vector_type(4))) float f32x4;
typedef __attribute__((ext_vector_type(8))) __bf16 bf16x8;

__device__ __forceinline__ unsigned short f2bf(float f) {
  __bf16 h = (__bf16)f;
  return __builtin_bit_cast(unsigned short, h);
}

__device__ __forceinline__ float fast_tanh(float x) {
  float e = __expf(2.0f * x);
  return 1.0f - 2.0f / (e + 1.0f);   // NaN-free at +-inf
}

__device__ __forceinline__ void gload_lds16(const void* gptr, void* lptr) {
  auto g = reinterpret_cast<const __attribute__((address_space(1))) unsigned int*>(
      reinterpret_cast<uintptr_t>(gptr));
  auto l = reinterpret_cast<__attribute__((address_space(3))) unsigned int*>(
      reinterpret_cast<uintptr_t>(lptr));
  __builtin_amdgcn_global_load_lds(g, l, 16, 0, 0);
}

// ---------- kernel 1: tq[b][h] += queries[b,k0:k0+256] . W_q[k0:k0+256,h] ----------
// grid 512: b = bx>>4, hc = (bx>>2)&3, ks = bx&3.  4-way atomic contention only.
__global__ __launch_bounds__(256) void tq_kernel(
    const float* __restrict__ q, const float* __restrict__ Wq, float* __restrict__ tq) {
  __shared__ float qs[256];
  int bx = blockIdx.x;
  int b = bx >> 4, hc = (bx >> 2) & 3, ks = bx & 3;
  int tid = threadIdx.x;
  int h = hc * 256 + tid;
  int k0 = ks * 256;
  qs[tid] = q[b * 1024 + k0 + tid];
  __syncthreads();
  float acc = 0.f;
  const float* wp = Wq + (size_t)k0 * 1024 + h;
#pragma unroll 8
  for (int k = 0; k < 256; ++k) acc = fmaf(qs[k], wp[(size_t)k * 1024], acc);
  atomicAdd(&tq[b * 1024 + h], acc);
}

// ---------- kernel 2: W_kT[h][k] = bf16(W_k[k][h]) ----------
__global__ __launch_bounds__(256) void wkt_kernel(
    const float* __restrict__ Wk, unsigned short* __restrict__ WkT) {
  __shared__ float tile[64][68];
  int kt = blockIdx.x & 15;
  int ht = blockIdx.x >> 4;
  int tid = threadIdx.x;
  int r = tid >> 4;
  int c = (tid & 15) * 4;
#pragma unroll
  for (int i = 0; i < 4; ++i) {
    int rr = i * 16 + r;
    f32x4 v = *(const f32x4*)(Wk + (size_t)(kt * 64 + rr) * 1024 + ht * 64 + c);
    tile[rr][c + 0] = v.x; tile[rr][c + 1] = v.y;
    tile[rr][c + 2] = v.z; tile[rr][c + 3] = v.w;
  }
  __syncthreads();
#pragma unroll
  for (int i = 0; i < 4; ++i) {
    int hh = i * 16 + r;
    ushort4 o;
    o.x = f2bf(tile[c + 0][hh]); o.y = f2bf(tile[c + 1][hh]);
    o.z = f2bf(tile[c + 2][hh]); o.w = f2bf(tile[c + 3][hh]);
    *(ushort4*)(WkT + (size_t)(ht * 64 + hh) * 1024 + kt * 64 + c) = o;
  }
}

// ---------- kernel 3: fused scores GEMM (m97 structure: single-buffer LDS, 4 blocks/CU) ----------
__global__ __launch_bounds__(256, 4) void score_kernel(
    const float* __restrict__ keys, const unsigned short* __restrict__ WkT,
    const float* __restrict__ tq, const float* __restrict__ wv,
    float* __restrict__ scores) {
  __shared__ unsigned short As[128 * 64];
  __shared__ unsigned short Bs[128 * 64];

  const int bid = blockIdx.x;
  const int xcd = bid & 7;
  const int j = bid >> 3;
  const int m_strip = xcd * 64 + (j >> 3);  // 0..511
  const int h_tile = j & 7;                 // 0..7
  const int row0 = m_strip * 128;
  const int col0 = h_tile * 128;
  const int b = row0 >> 11;

  const int tid = threadIdx.x;
  const int lane = tid & 63;
  const int w = tid >> 6;

  // A staging: 1024 16B-chunks (128 rows x 8 slots), 4 per thread.
  // LDS swizzle convention: storage slot s of row r holds data slot s^(r&7).
  int a_r[4], a_ss[4], a_dst[4];
#pragma unroll
  for (int c = 0; c < 4; ++c) {
    int q = c * 256 + tid;
    int r = q >> 3, slot = q & 7;
    a_r[c] = r;
    a_ss[c] = slot ^ (r & 7);
    a_dst[c] = r * 64 + slot * 8;
  }

  f32x4 fa[4][2];

  auto A_issue = [&](int kt) {
#pragma unroll
    for (int c = 0; c < 4; ++c) {
      const float* src = keys + (size_t)(row0 + a_r[c]) * 1024 + kt * 64 + a_ss[c] * 8;
      fa[c][0] = *(const f32x4*)(src);
      fa[c][1] = *(const f32x4*)(src + 4);
    }
  };
  auto A_write = [&]() {
#pragma unroll
    for (int c = 0; c < 4; ++c) {
      bf16x8 v;
#pragma unroll
      for (int e = 0; e < 4; ++e) {
        v[e] = (__bf16)fa[c][0][e];
        v[4 + e] = (__bf16)fa[c][1][e];
      }
      *(bf16x8*)(&As[a_dst[c]]) = v;
    }
  };
  auto B_issue = [&](int kt) {
    // wave w stages rows [w*32, w*32+32); linear LDS dest, pre-swizzled global src (m173)
#pragma unroll
    for (int i = 0; i < 4; ++i) {
      int n = w * 32 + i * 8 + (lane >> 3);
      int ss = (lane & 7) ^ (n & 7);
      const unsigned short* g = WkT + (size_t)(col0 + n) * 1024 + kt * 64 + ss * 8;
      gload_lds16(g, &Bs[(w * 32 + i * 8) * 64]);
    }
  };

  // prologue: tile 0 into LDS, tile 1 into regs
  A_issue(0);
  B_issue(0);
  A_write();
  A_issue(1);
  __syncthreads();   // drains vmcnt (B tile 0) + lgkm (A writes)

  f32x4 acc[4][4];
#pragma unroll
  for (int m = 0; m < 4; ++m)
#pragma unroll
    for (int n = 0; n < 4; ++n) acc[m][n] = (f32x4){0.f, 0.f, 0.f, 0.f};

  const int m_half = (w >> 1) * 64;
  const int n_half = (w & 1) * 64;
  const int lrow = lane & 15;
  const int lk = lane >> 4;

  for (int kt = 0; kt < 16; ++kt) {
#pragma unroll
    for (int kk = 0; kk < 2; ++kk) {
      bf16x8 af[4], bfr[4];
#pragma unroll
      for (int m = 0; m < 4; ++m) {
        int r = m_half + m * 16 + lrow;
        int slot = (kk * 4 + lk) ^ (r & 7);
        af[m] = *(const bf16x8*)(&As[r * 64 + slot * 8]);
      }
#pragma unroll
      for (int n = 0; n < 4; ++n) {
        int r = n_half + n * 16 + lrow;
        int slot = (kk * 4 + lk) ^ (r & 7);
        bfr[n] = *(const bf16x8*)(&Bs[r * 64 + slot * 8]);
      }
#pragma unroll
      for (int m = 0; m < 4; ++m)
#pragma unroll
        for (int n = 0; n < 4; ++n)
          acc[m][n] = __builtin_amdgcn_mfma_f32_16x16x32_bf16(af[m], bfr[n], acc[m][n], 0, 0, 0);
    }
    __syncthreads();           // all waves done reading tile kt
    if (kt < 15) {
      A_write();               // write tile kt+1 (regs were issued one step ago)
      B_issue(kt + 1);
      if (kt < 14) A_issue(kt + 2);  // issue-early (T14)
      __syncthreads();         // drains B vmcnt + A lgkm
    }
  }

  // epilogue: tanh(acc + tq) * wv, reduce over columns, atomicAdd per row
  float tql[4], wvl[4];
#pragma unroll
  for (int n = 0; n < 4; ++n) {
    int h = col0 + n_half + n * 16 + lrow;
    tql[n] = tq[b * 1024 + h];
    wvl[n] = wv[h];
  }
  float rs[4][4];
#pragma unroll
  for (int m = 0; m < 4; ++m)
#pragma unroll
    for (int jj = 0; jj < 4; ++jj) rs[m][jj] = 0.f;
#pragma unroll
  for (int m = 0; m < 4; ++m)
#pragma unroll
    for (int n = 0; n < 4; ++n)
#pragma unroll
      for (int jj = 0; jj < 4; ++jj)
        rs[m][jj] += fast_tanh(acc[m][n][jj] + tql[n]) * wvl[n];
#pragma unroll
  for (int m = 0; m < 4; ++m)
#pragma unroll
    for (int jj = 0; jj < 4; ++jj) {
      float v = rs[m][jj];
      v += __shfl_xor(v, 1);
      v += __shfl_xor(v, 2);
      v += __shfl_xor(v, 4);
      v += __shfl_xor(v, 8);
      rs[m][jj] = v;
    }
  if ((lane & 15) == 0) {
#pragma unroll
    for (int m = 0; m < 4; ++m)
#pragma unroll
      for (int jj = 0; jj < 4; ++jj)
        atomicAdd(&scores[row0 + m_half + m * 16 + lk * 4 + jj], rs[m][jj]);
  }
}

// ---------- kernel 4: masked softmax over T per batch ----------
__global__ __launch_bounds__(256) void softmax_kernel(
    const float* __restrict__ scores, const int* __restrict__ mask,
    float* __restrict__ attn) {
  int b = blockIdx.x;
  int tid = threadIdx.x;
  int lane = tid & 63, wid = tid >> 6;
  __shared__ float red[4];
  float loc[8];
  float mx = -1e30f;
#pragma unroll
  for (int i = 0; i < 8; ++i) {
    int t = i * 256 + tid;
    float s = scores[b * 2048 + t];
    if (mask[b * 2048 + t] != 0) s = -INFINITY;
    loc[i] = s;
    mx = fmaxf(mx, s);
  }
#pragma unroll
  for (int d = 1; d < 64; d <<= 1) mx = fmaxf(mx, __shfl_xor(mx, d));
  if (lane == 0) red[wid] = mx;
  __syncthreads();
  mx = fmaxf(fmaxf(red[0], red[1]), fmaxf(red[2], red[3]));
  __syncthreads();
  float sum = 0.f;
#pragma unroll
  for (int i = 0; i < 8; ++i) {
    float e = __expf(loc[i] - mx);
    loc[i] = e;
    sum += e;
  }
#pragma unroll
  for (int d = 1; d < 64; d <<= 1) sum += __shfl_xor(sum, d);
  if (lane == 0) red[wid] = sum;
  __syncthreads();
  sum = red[0] + red[1] + red[2] + red[3];
  float inv = 1.f / sum;
#pragma unroll
  for (int i = 0; i < 8; ++i) attn[b * 2048 + i * 256 + tid] = loc[i] * inv;
}

// ---------- kernel 5a: partial[b][tc][k] = sum_{t in chunk} keys[b][t][k] * attn[b][t] ----------
__global__ __launch_bounds__(256) void context_kernel(
    const float* __restrict__ keys, const float* __restrict__ attn,
    float* __restrict__ partial) {
  int bid = blockIdx.x;
  int b = bid >> 5, ts = bid & 31;
  int tid = threadIdx.x;
  const float* kp = keys + (size_t)b * 2048 * 1024 + (size_t)ts * 64 * 1024 + tid * 4;
  const float* ap = attn + b * 2048 + ts * 64;
  f32x4 acc = {0.f, 0.f, 0.f, 0.f};
#pragma unroll 4
  for (int i = 0; i < 64; ++i) {
    float wgt = ap[i];
    if (wgt != 0.f) {  // masked rows have weight exactly 0 -> skip load (uniform branch)
      f32x4 kv = *(const f32x4*)(kp + (size_t)i * 1024);
      acc += kv * wgt;
    }
  }
  *(f32x4*)(partial + (size_t)(b * 32 + ts) * 1024 + tid * 4) = acc;
}

// ---------- kernel 5b: ctx[b][k] = sum_tc partial[b][tc][k] ----------
__global__ __launch_bounds__(256) void ctx_reduce_kernel(
    const float* __restrict__ partial, float* __restrict__ ctx) {
  int o = blockIdx.x * 256 + threadIdx.x;  // 32768 outputs
  int b = o >> 10, k = o & 1023;
  float s = 0.f;
#pragma unroll 8
  for (int tc = 0; tc < 32; ++tc) s += partial[(size_t)(b * 32 + tc) * 1024 + k];
  ctx[o] = s;
}

extern "C" void kernel_launch(void* const* d_in, const int* in_sizes, int n_in,
                              void* d_out, int out_size, void* d_ws, size_t ws_size,
                              hipStream_t stream) {
  const float* queries = (const float*)d_in[0];
  const float* keys    = (const float*)d_in[1];
  const int*   mask    = (const int*)d_in[2];
  const float* Wq      = (const float*)d_in[3];
  const float* Wk      = (const float*)d_in[4];
  const float* wv      = (const float*)d_in[5];

  float* out  = (float*)d_out;
  float* attn = out;            // B*T   = 65536 floats
  float* ctx  = out + 65536;    // B*K   = 32768 floats

  char* ws = (char*)d_ws;
  float* tq             = (float*)ws;                                  // 128 KB
  float* scores         = (float*)(ws + (128 << 10));                  // 256 KB
  unsigned short* WkT   = (unsigned short*)(ws + (384 << 10));         // 2 MB
  float* partial        = (float*)(ws + (384 << 10) + (2 << 20));      // 4 MB

  hipMemsetAsync(tq, 0, 32768 * sizeof(float), stream);
  hipMemsetAsync(scores, 0, 65536 * sizeof(float), stream);

  tq_kernel<<<512, 256, 0, stream>>>(queries, Wq, tq);
  wkt_kernel<<<256, 256, 0, stream>>>(Wk, WkT);
  score_kernel<<<4096, 256, 0, stream>>>(keys, WkT, tq, wv, scores);
  softmax_kernel<<<32, 256, 0, stream>>>(scores, mask, attn);
  context_kernel<<<1024, 256, 0, stream>>>(keys, attn, partial);
  ctx_reduce_kernel<<<128, 256, 0, stream>>>(partial, ctx);
}

// Round 6
// 588.141 us; speedup vs baseline: 1.3037x; 1.3037x over previous
//
#include <hip/hip_runtime.h>
#include <hip/hip_bf16.h>

#define NB 32
#define NT 2048
#define NH 1024

typedef __attribute__((ext_vector_type(4))) float f32x4;
typedef __attribute__((ext_vector_type(8))) __bf16 bf16x8;

#define SBAR() __builtin_amdgcn_sched_barrier(0)

__device__ __forceinline__ unsigned short f2bf(float f) {
  __bf16 h = (__bf16)f;
  return __builtin_bit_cast(unsigned short, h);
}

__device__ __forceinline__ float fast_tanh(float x) {
  float e = __expf(2.0f * x);
  return 1.0f - 2.0f / (e + 1.0f);   // NaN-free at +-inf
}

__device__ __forceinline__ void gload_lds16(const void* gptr, void* lptr) {
  auto g = reinterpret_cast<const __attribute__((address_space(1))) unsigned int*>(
      reinterpret_cast<uintptr_t>(gptr));
  auto l = reinterpret_cast<__attribute__((address_space(3))) unsigned int*>(
      reinterpret_cast<uintptr_t>(lptr));
  __builtin_amdgcn_global_load_lds(g, l, 16, 0, 0);
}

// ---------- kernel 1: tq[b][h] += queries[b,k0:k0+256] . W_q[k0:k0+256,h] ----------
__global__ __launch_bounds__(256) void tq_kernel(
    const float* __restrict__ q, const float* __restrict__ Wq, float* __restrict__ tq) {
  __shared__ float qs[256];
  int bx = blockIdx.x;
  int b = bx >> 4, hc = (bx >> 2) & 3, ks = bx & 3;
  int tid = threadIdx.x;
  int h = hc * 256 + tid;
  int k0 = ks * 256;
  qs[tid] = q[b * 1024 + k0 + tid];
  __syncthreads();
  float acc = 0.f;
  const float* wp = Wq + (size_t)k0 * 1024 + h;
#pragma unroll 8
  for (int k = 0; k < 256; ++k) acc = fmaf(qs[k], wp[(size_t)k * 1024], acc);
  atomicAdd(&tq[b * 1024 + h], acc);
}

// ---------- kernel 2: W_kT[h][k] = bf16(W_k[k][h]) ----------
__global__ __launch_bounds__(256) void wkt_kernel(
    const float* __restrict__ Wk, unsigned short* __restrict__ WkT) {
  __shared__ float tile[64][68];
  int kt = blockIdx.x & 15;
  int ht = blockIdx.x >> 4;
  int tid = threadIdx.x;
  int r = tid >> 4;
  int c = (tid & 15) * 4;
#pragma unroll
  for (int i = 0; i < 4; ++i) {
    int rr = i * 16 + r;
    f32x4 v = *(const f32x4*)(Wk + (size_t)(kt * 64 + rr) * 1024 + ht * 64 + c);
    tile[rr][c + 0] = v.x; tile[rr][c + 1] = v.y;
    tile[rr][c + 2] = v.z; tile[rr][c + 3] = v.w;
  }
  __syncthreads();
#pragma unroll
  for (int i = 0; i < 4; ++i) {
    int hh = i * 16 + r;
    ushort4 o;
    o.x = f2bf(tile[c + 0][hh]); o.y = f2bf(tile[c + 1][hh]);
    o.z = f2bf(tile[c + 2][hh]); o.w = f2bf(tile[c + 3][hh]);
    *(ushort4*)(WkT + (size_t)(ht * 64 + hh) * 1024 + kt * 64 + c) = o;
  }
}

// ---------- kernel 3: fused scores GEMM ----------
// Single-buffer 32KB LDS, reg-staged A (f32->bf16), gload_lds B, (256,3).
// Round-4 post-timing divergence => staging/read ordering made EXPLICIT:
// sched_barrier walls + inline s_waitcnt before each __syncthreads so
// correctness never depends on what waits hipcc chooses to emit.
__global__ __launch_bounds__(256, 3) void score_kernel(
    const float* __restrict__ keys, const unsigned short* __restrict__ WkT,
    const float* __restrict__ tq, const float* __restrict__ wv,
    float* __restrict__ scores) {
  __shared__ unsigned short As[128 * 64];
  __shared__ unsigned short Bs[128 * 64];

  const int bid = blockIdx.x;
  const int xcd = bid & 7;
  const int j = bid >> 3;
  const int m_strip = xcd * 64 + (j >> 3);  // 0..511; 8 h-tiles of one strip share an XCD
  const int h_tile = j & 7;                 // 0..7
  const int row0 = m_strip * 128;
  const int col0 = h_tile * 128;
  const int b = row0 >> 11;

  const int tid = threadIdx.x;
  const int lane = tid & 63;
  const int w = tid >> 6;

  // A staging: 1024 16B-chunks (128 rows x 8 slots), 4 per thread.
  // LDS swizzle convention: storage slot s of row r holds data slot s^(r&7).
  int a_r[4], a_ss[4], a_dst[4];
#pragma unroll
  for (int c = 0; c < 4; ++c) {
    int q = c * 256 + tid;
    int r = q >> 3, slot = q & 7;
    a_r[c] = r;
    a_ss[c] = slot ^ (r & 7);
    a_dst[c] = r * 64 + slot * 8;
  }

  f32x4 fa[4][2];

  auto A_issue = [&](int kt) {
#pragma unroll
    for (int c = 0; c < 4; ++c) {
      const float* src = keys + (size_t)(row0 + a_r[c]) * 1024 + kt * 64 + a_ss[c] * 8;
      fa[c][0] = *(const f32x4*)(src);
      fa[c][1] = *(const f32x4*)(src + 4);
    }
  };
  auto A_write = [&]() {
#pragma unroll
    for (int c = 0; c < 4; ++c) {
      bf16x8 v;
#pragma unroll
      for (int e = 0; e < 4; ++e) {
        v[e] = (__bf16)fa[c][0][e];
        v[4 + e] = (__bf16)fa[c][1][e];
      }
      *(bf16x8*)(&As[a_dst[c]]) = v;
    }
  };
  auto B_issue = [&](int kt) {
    // wave w stages rows [w*32, w*32+32); linear LDS dest, pre-swizzled global src (m173)
#pragma unroll
    for (int i = 0; i < 4; ++i) {
      int n = w * 32 + i * 8 + (lane >> 3);
      int ss = (lane & 7) ^ (n & 7);
      const unsigned short* g = WkT + (size_t)(col0 + n) * 1024 + kt * 64 + ss * 8;
      gload_lds16(g, &Bs[(w * 32 + i * 8) * 64]);
    }
  };

  // prologue: tile 0 into LDS, tile 1 into regs
  A_issue(0);          // 8 vm loads -> fa
  SBAR();
  B_issue(0);          // 4 gload_lds -> Bs (older than fa(1) below)
  SBAR();
  A_write();           // compiler waits fa(0); ds_write As
  SBAR();
  A_issue(1);          // 8 vm loads -> fa (youngest)
  SBAR();
  // retire the 4 B gloads + ds_writes; keep fa(1) in flight
  asm volatile("s_waitcnt vmcnt(8) lgkmcnt(0)" ::: "memory");
  SBAR();
  __syncthreads();
  SBAR();

  f32x4 acc[4][4];
#pragma unroll
  for (int m = 0; m < 4; ++m)
#pragma unroll
    for (int n = 0; n < 4; ++n) acc[m][n] = (f32x4){0.f, 0.f, 0.f, 0.f};

  const int m_half = (w >> 1) * 64;
  const int n_half = (w & 1) * 64;
  const int lrow = lane & 15;
  const int lk = lane >> 4;

  for (int kt = 0; kt < 16; ++kt) {
#pragma unroll
    for (int kk = 0; kk < 2; ++kk) {
      bf16x8 af[4], bfr[4];
#pragma unroll
      for (int m = 0; m < 4; ++m) {
        int r = m_half + m * 16 + lrow;
        int slot = (kk * 4 + lk) ^ (r & 7);
        af[m] = *(const bf16x8*)(&As[r * 64 + slot * 8]);
      }
#pragma unroll
      for (int n = 0; n < 4; ++n) {
        int r = n_half + n * 16 + lrow;
        int slot = (kk * 4 + lk) ^ (r & 7);
        bfr[n] = *(const bf16x8*)(&Bs[r * 64 + slot * 8]);
      }
#pragma unroll
      for (int m = 0; m < 4; ++m)
#pragma unroll
        for (int n = 0; n < 4; ++n)
          acc[m][n] = __builtin_amdgcn_mfma_f32_16x16x32_bf16(af[m], bfr[n], acc[m][n], 0, 0, 0);
    }
    // barrier #1: all waves done ds_reading tile kt (reads already consumed by MFMA)
    SBAR();
    __syncthreads();
    SBAR();
    if (kt < 15) {
      A_write();               // ds_write fa(kt+1) -> As (compiler waits fa)
      SBAR();
      B_issue(kt + 1);         // 4 gload_lds -> Bs
      SBAR();
      if (kt < 14) {
        A_issue(kt + 2);       // 8 vm loads -> fa, younger than the B gloads
        SBAR();
        // retire 4 B gloads + A ds_writes; keep 8 fa loads flying
        asm volatile("s_waitcnt vmcnt(8) lgkmcnt(0)" ::: "memory");
      } else {
        // no prefetch issued: counted wait would be a no-op -> full drain
        asm volatile("s_waitcnt vmcnt(0) lgkmcnt(0)" ::: "memory");
      }
      SBAR();
      __syncthreads();         // barrier #2: As/Bs tile kt+1 visible to all waves
      SBAR();
    }
  }

  // epilogue: tanh(acc + tq) * wv, reduce over columns, atomicAdd per row
  float tql[4], wvl[4];
#pragma unroll
  for (int n = 0; n < 4; ++n) {
    int h = col0 + n_half + n * 16 + lrow;
    tql[n] = tq[b * 1024 + h];
    wvl[n] = wv[h];
  }
  float rs[4][4];
#pragma unroll
  for (int m = 0; m < 4; ++m)
#pragma unroll
    for (int jj = 0; jj < 4; ++jj) rs[m][jj] = 0.f;
#pragma unroll
  for (int m = 0; m < 4; ++m)
#pragma unroll
    for (int n = 0; n < 4; ++n)
#pragma unroll
      for (int jj = 0; jj < 4; ++jj)
        rs[m][jj] += fast_tanh(acc[m][n][jj] + tql[n]) * wvl[n];
#pragma unroll
  for (int m = 0; m < 4; ++m)
#pragma unroll
    for (int jj = 0; jj < 4; ++jj) {
      float v = rs[m][jj];
      v += __shfl_xor(v, 1);
      v += __shfl_xor(v, 2);
      v += __shfl_xor(v, 4);
      v += __shfl_xor(v, 8);
      rs[m][jj] = v;
    }
  if ((lane & 15) == 0) {
#pragma unroll
    for (int m = 0; m < 4; ++m)
#pragma unroll
      for (int jj = 0; jj < 4; ++jj)
        atomicAdd(&scores[row0 + m_half + m * 16 + lk * 4 + jj], rs[m][jj]);
  }
}

// ---------- kernel 4: masked softmax over T per batch ----------
__global__ __launch_bounds__(256) void softmax_kernel(
    const float* __restrict__ scores, const int* __restrict__ mask,
    float* __restrict__ attn) {
  int b = blockIdx.x;
  int tid = threadIdx.x;
  int lane = tid & 63, wid = tid >> 6;
  __shared__ float red[4];
  float loc[8];
  float mx = -1e30f;
#pragma unroll
  for (int i = 0; i < 8; ++i) {
    int t = i * 256 + tid;
    float s = scores[b * 2048 + t];
    if (mask[b * 2048 + t] != 0) s = -INFINITY;
    loc[i] = s;
    mx = fmaxf(mx, s);
  }
#pragma unroll
  for (int d = 1; d < 64; d <<= 1) mx = fmaxf(mx, __shfl_xor(mx, d));
  if (lane == 0) red[wid] = mx;
  __syncthreads();
  mx = fmaxf(fmaxf(red[0], red[1]), fmaxf(red[2], red[3]));
  __syncthreads();
  float sum = 0.f;
#pragma unroll
  for (int i = 0; i < 8; ++i) {
    float e = __expf(loc[i] - mx);
    loc[i] = e;
    sum += e;
  }
#pragma unroll
  for (int d = 1; d < 64; d <<= 1) sum += __shfl_xor(sum, d);
  if (lane == 0) red[wid] = sum;
  __syncthreads();
  sum = red[0] + red[1] + red[2] + red[3];
  float inv = 1.f / sum;
#pragma unroll
  for (int i = 0; i < 8; ++i) attn[b * 2048 + i * 256 + tid] = loc[i] * inv;
}

// ---------- kernel 5a: partial[b][tc][k] = sum_{t in chunk} keys[b][t][k] * attn[b][t] ----------
__global__ __launch_bounds__(256) void context_kernel(
    const float* __restrict__ keys, const float* __restrict__ attn,
    float* __restrict__ partial) {
  int bid = blockIdx.x;
  int b = bid >> 5, ts = bid & 31;
  int tid = threadIdx.x;
  const float* kp = keys + (size_t)b * 2048 * 1024 + (size_t)ts * 64 * 1024 + tid * 4;
  const float* ap = attn + b * 2048 + ts * 64;
  f32x4 acc = {0.f, 0.f, 0.f, 0.f};
#pragma unroll 4
  for (int i = 0; i < 64; ++i) {
    float wgt = ap[i];
    if (wgt != 0.f) {  // masked rows have weight exactly 0 -> skip load (uniform branch)
      f32x4 kv = *(const f32x4*)(kp + (size_t)i * 1024);
      acc += kv * wgt;
    }
  }
  *(f32x4*)(partial + (size_t)(b * 32 + ts) * 1024 + tid * 4) = acc;
}

// ---------- kernel 5b: ctx[b][k] = sum_tc partial[b][tc][k] ----------
__global__ __launch_bounds__(256) void ctx_reduce_kernel(
    const float* __restrict__ partial, float* __restrict__ ctx) {
  int o = blockIdx.x * 256 + threadIdx.x;  // 32768 outputs
  int b = o >> 10, k = o & 1023;
  float s = 0.f;
#pragma unroll 8
  for (int tc = 0; tc < 32; ++tc) s += partial[(size_t)(b * 32 + tc) * 1024 + k];
  ctx[o] = s;
}

extern "C" void kernel_launch(void* const* d_in, const int* in_sizes, int n_in,
                              void* d_out, int out_size, void* d_ws, size_t ws_size,
                              hipStream_t stream) {
  const float* queries = (const float*)d_in[0];
  const float* keys    = (const float*)d_in[1];
  const int*   mask    = (const int*)d_in[2];
  const float* Wq      = (const float*)d_in[3];
  const float* Wk      = (const float*)d_in[4];
  const float* wv      = (const float*)d_in[5];

  float* out  = (float*)d_out;
  float* attn = out;            // B*T   = 65536 floats
  float* ctx  = out + 65536;    // B*K   = 32768 floats

  char* ws = (char*)d_ws;
  float* tq             = (float*)ws;                                  // 128 KB
  float* scores         = (float*)(ws + (128 << 10));                  // 256 KB
  unsigned short* WkT   = (unsigned short*)(ws + (384 << 10));         // 2 MB
  float* partial        = (float*)(ws + (384 << 10) + (2 << 20));      // 4 MB

  hipMemsetAsync(tq, 0, 32768 * sizeof(float), stream);
  hipMemsetAsync(scores, 0, 65536 * sizeof(float), stream);

  tq_kernel<<<512, 256, 0, stream>>>(queries, Wq, tq);
  wkt_kernel<<<256, 256, 0, stream>>>(Wk, WkT);
  score_kernel<<<4096, 256, 0, stream>>>(keys, WkT, tq, wv, scores);
  softmax_kernel<<<32, 256, 0, stream>>>(scores, mask, attn);
  context_kernel<<<1024, 256, 0, stream>>>(keys, attn, partial);
  ctx_reduce_kernel<<<128, 256, 0, stream>>>(partial, ctx);
}